// Round 6
// baseline (415.367 us; speedup 1.0000x reference)
//
#include <hip/hip_runtime.h>
#include <hip/hip_bf16.h>
#include <math.h>

// ---------------------------------------------------------------------------
// Sizes (fixed by the problem)
#define Bq 256
#define DIM_IN 1024
#define DIM_GLOBAL 1024
#define UNITS 512
#define DD 16
#define GG 8
// d_out layout: attention [256*512*16] | weights [256*256*512] | outputs [256*512*16]
#define ATT_ELEMS (256*512*16)       // 2,097,152
#define W_ELEMS   (256*256*512)      // 33,554,432

typedef __attribute__((ext_vector_type(8))) short bf16x8;
typedef __attribute__((ext_vector_type(4))) float f32x4;

__device__ __forceinline__ short f2bf(float f) {
    union { float f; unsigned u; } v; v.f = f;
    unsigned u = v.u;
    u += 0x7fffu + ((u >> 16) & 1u);   // round-to-nearest-even
    return (short)(u >> 16);
}

__device__ __forceinline__ unsigned pk2(float a, float b) {
    return (unsigned)(unsigned short)f2bf(a) | ((unsigned)(unsigned short)f2bf(b) << 16);
}

// ---------------------------------------------------------------------------
// zero h (256x1024 floats = 65536 float4)
__global__ __launch_bounds__(256) void zero_h(float4* p) {
    p[blockIdx.x * 256 + threadIdx.x] = make_float4(0.f, 0.f, 0.f, 0.f);
}

// ---------------------------------------------------------------------------
// gemm1 split-K: C[M,N] += A[M,K/4-slice] @ B + (bias once, kq==0).
// grid (N/64, M/64, 4); 64x64 tile, BK=32; epilogue via atomicAdd into
// pre-zeroed C. 256 blocks -> all CUs busy (was 64 blocks).
#define BK 32
#define ASTR 40

__global__ __launch_bounds__(256) void gemm1_splitk(
    const float* __restrict__ A, const float* __restrict__ B,
    const float* __restrict__ bias, float* __restrict__ C,
    int M, int N, int K)
{
    __shared__ __align__(16) short As[64 * ASTR];
    __shared__ __align__(16) short Bs[64 * ASTR];

    const int t = threadIdx.x;
    const int lane = t & 63;
    const int wave = t >> 6;
    const int m0 = blockIdx.y * 64;
    const int n0 = blockIdx.x * 64;
    const int kq = blockIdx.z;             // k-quarter

    const int wm = (wave >> 1) * 32;
    const int wn = (wave & 1) * 32;
    const int fl = lane & 15;
    const int ko = lane >> 4;

    f32x4 acc00 = {}, acc01 = {}, acc10 = {}, acc11 = {};

    const int ar = t >> 2;
    const int aq = (t & 3) * 8;
    const int bn = t & 63;
    const int bk = (t >> 6) * 8;

    const int kbeg = kq * 256;
    for (int k0 = kbeg; k0 < kbeg + 256; k0 += BK) {
        __syncthreads();
        {
            const float* src = A + (size_t)(m0 + ar) * K + k0 + aq;
            float4 v0 = *(const float4*)(src);
            float4 v1 = *(const float4*)(src + 4);
            bf16x8 p;
            p[0]=f2bf(v0.x); p[1]=f2bf(v0.y); p[2]=f2bf(v0.z); p[3]=f2bf(v0.w);
            p[4]=f2bf(v1.x); p[5]=f2bf(v1.y); p[6]=f2bf(v1.z); p[7]=f2bf(v1.w);
            *(bf16x8*)(&As[ar * ASTR + aq]) = p;
        }
        {
            const float* src = B + (size_t)(k0 + bk) * N + n0 + bn;
            bf16x8 p;
            #pragma unroll
            for (int j = 0; j < 8; j++) p[j] = f2bf(src[(size_t)j * N]);
            *(bf16x8*)(&Bs[bn * ASTR + bk]) = p;
        }
        __syncthreads();

        bf16x8 a0 = *(const bf16x8*)(&As[(wm + 0  + fl) * ASTR + ko * 8]);
        bf16x8 a1 = *(const bf16x8*)(&As[(wm + 16 + fl) * ASTR + ko * 8]);
        bf16x8 b0 = *(const bf16x8*)(&Bs[(wn + 0  + fl) * ASTR + ko * 8]);
        bf16x8 b1 = *(const bf16x8*)(&Bs[(wn + 16 + fl) * ASTR + ko * 8]);
        acc00 = __builtin_amdgcn_mfma_f32_16x16x32_bf16(a0, b0, acc00, 0, 0, 0);
        acc01 = __builtin_amdgcn_mfma_f32_16x16x32_bf16(a0, b1, acc01, 0, 0, 0);
        acc10 = __builtin_amdgcn_mfma_f32_16x16x32_bf16(a1, b0, acc10, 0, 0, 0);
        acc11 = __builtin_amdgcn_mfma_f32_16x16x32_bf16(a1, b1, acc11, 0, 0, 0);
    }

    const float bz = (kq == 0) ? 1.f : 0.f;
    #pragma unroll
    for (int r = 0; r < 4; r++) {
        int mrow = m0 + wm + ko * 4 + r;
        int ncol = n0 + wn + fl;
        atomicAdd(&C[(size_t)(mrow     ) * N + (ncol     )], acc00[r] + bz * bias[ncol]);
        atomicAdd(&C[(size_t)(mrow     ) * N + (ncol + 16)], acc01[r] + bz * bias[ncol + 16]);
        atomicAdd(&C[(size_t)(mrow + 16) * N + (ncol     )], acc10[r] + bz * bias[ncol]);
        atomicAdd(&C[(size_t)(mrow + 16) * N + (ncol + 16)], acc11[r] + bz * bias[ncol + 16]);
    }
}

// ---------------------------------------------------------------------------
// gemm2: C = A @ B + bias, 64x64 tile, BK=64 (half the barriers of BK=32,
// 8 MFMAs per wave per stage). grid (N/64, M/64).
#define STR2 72   // shorts per row (64 + 8 pad), 144B, 16B-divisible

__global__ __launch_bounds__(256) void gemm_bias_bk64(
    const float* __restrict__ A, const float* __restrict__ B,
    const float* __restrict__ bias, float* __restrict__ C,
    int M, int N, int K)
{
    __shared__ __align__(16) short As[64 * STR2];
    __shared__ __align__(16) short Bs[64 * STR2];

    const int t = threadIdx.x;
    const int lane = t & 63;
    const int wave = t >> 6;
    const int m0 = blockIdx.y * 64;
    const int n0 = blockIdx.x * 64;

    const int wm = (wave >> 1) * 32;
    const int wn = (wave & 1) * 32;
    const int fl = lane & 15;
    const int ko = lane >> 4;

    f32x4 acc00 = {}, acc01 = {}, acc10 = {}, acc11 = {};

    const int ar = t >> 3;             // 0..31 (rows ar, ar+32)
    const int aq = (t & 7) * 8;        // k offset 0..56
    const int bn = t & 63;
    const int bk = (t >> 6) * 8;       // 0,8,16,24 (+32 for second)

    for (int k0 = 0; k0 < K; k0 += 64) {
        __syncthreads();
        #pragma unroll
        for (int h = 0; h < 2; h++) {
            const float* src = A + (size_t)(m0 + ar + h*32) * K + k0 + aq;
            float4 v0 = *(const float4*)(src);
            float4 v1 = *(const float4*)(src + 4);
            bf16x8 p;
            p[0]=f2bf(v0.x); p[1]=f2bf(v0.y); p[2]=f2bf(v0.z); p[3]=f2bf(v0.w);
            p[4]=f2bf(v1.x); p[5]=f2bf(v1.y); p[6]=f2bf(v1.z); p[7]=f2bf(v1.w);
            *(bf16x8*)(&As[(ar + h*32) * STR2 + aq]) = p;
        }
        #pragma unroll
        for (int h = 0; h < 2; h++) {
            const float* src = B + (size_t)(k0 + bk + h*32) * N + n0 + bn;
            bf16x8 p;
            #pragma unroll
            for (int j = 0; j < 8; j++) p[j] = f2bf(src[(size_t)j * N]);
            *(bf16x8*)(&Bs[bn * STR2 + bk + h*32]) = p;
        }
        __syncthreads();

        bf16x8 a00 = *(const bf16x8*)(&As[(wm + 0  + fl) * STR2 + ko * 8]);
        bf16x8 a01 = *(const bf16x8*)(&As[(wm + 0  + fl) * STR2 + ko * 8 + 32]);
        bf16x8 a10 = *(const bf16x8*)(&As[(wm + 16 + fl) * STR2 + ko * 8]);
        bf16x8 a11 = *(const bf16x8*)(&As[(wm + 16 + fl) * STR2 + ko * 8 + 32]);
        bf16x8 b00 = *(const bf16x8*)(&Bs[(wn + 0  + fl) * STR2 + ko * 8]);
        bf16x8 b01 = *(const bf16x8*)(&Bs[(wn + 0  + fl) * STR2 + ko * 8 + 32]);
        bf16x8 b10 = *(const bf16x8*)(&Bs[(wn + 16 + fl) * STR2 + ko * 8]);
        bf16x8 b11 = *(const bf16x8*)(&Bs[(wn + 16 + fl) * STR2 + ko * 8 + 32]);
        acc00 = __builtin_amdgcn_mfma_f32_16x16x32_bf16(a00, b00, acc00, 0, 0, 0);
        acc00 = __builtin_amdgcn_mfma_f32_16x16x32_bf16(a01, b01, acc00, 0, 0, 0);
        acc01 = __builtin_amdgcn_mfma_f32_16x16x32_bf16(a00, b10, acc01, 0, 0, 0);
        acc01 = __builtin_amdgcn_mfma_f32_16x16x32_bf16(a01, b11, acc01, 0, 0, 0);
        acc10 = __builtin_amdgcn_mfma_f32_16x16x32_bf16(a10, b00, acc10, 0, 0, 0);
        acc10 = __builtin_amdgcn_mfma_f32_16x16x32_bf16(a11, b01, acc10, 0, 0, 0);
        acc11 = __builtin_amdgcn_mfma_f32_16x16x32_bf16(a10, b10, acc11, 0, 0, 0);
        acc11 = __builtin_amdgcn_mfma_f32_16x16x32_bf16(a11, b11, acc11, 0, 0, 0);
    }

    #pragma unroll
    for (int r = 0; r < 4; r++) {
        int mrow = m0 + wm + ko * 4 + r;
        int ncol = n0 + wn + fl;
        C[(size_t)(mrow     ) * N + (ncol     )] = acc00[r] + bias[ncol];
        C[(size_t)(mrow     ) * N + (ncol + 16)] = acc01[r] + bias[ncol + 16];
        C[(size_t)(mrow + 16) * N + (ncol     )] = acc10[r] + bias[ncol];
        C[(size_t)(mrow + 16) * N + (ncol + 16)] = acc11[r] + bias[ncol + 16];
    }
}

// ---------------------------------------------------------------------------
// v6 attn: MFMA attention with DIRECT weights write (no scratch, no transpose
// kernel). Block = 512 threads = 8 waves sharing one bt; wave wv owns
// u = u0 + wv (8 consecutive u per block). Per 32-m tile (p2), each wave
// stages its w values into a padded LDS buffer [m32][b16][u8+pad]; after one
// barrier the whole block flushes w[b][m][u0..u0+7] as 32B segments (two
// float4 per thread) -- L2 merges adjacent u-octets into full lines.
// QK/PV math identical to v5 (zero-shuffle permuted-k paired-tile PV).
#define L2E 1.4426950408889634f
#define UPAD 9

__global__ __launch_bounds__(512) void attn_mfma_fused(
    const float* __restrict__ attention,   // [256,512,16]
    const float* __restrict__ mem_att,     // [256,512,16]
    const float* __restrict__ mem_val,     // [256,512,16]
    const float* __restrict__ temperature, // [512]
    float* __restrict__ weights_out,       // [256,256,512]
    float* __restrict__ outputs_out)       // [256,512,16]
{
    __shared__ float wlds[2][32 * 16 * UPAD];   // 2 x 18,432 B

    const int t    = threadIdx.x;
    const int lane = t & 63;
    const int lq   = lane >> 4;
    const int lr   = lane & 15;
    const int wv   = t >> 6;               // 0..7 -> u slot
    // bijective XCD swizzle: 1024 blocks = 8 XCDs x 128; XCD x -> u in
    // [64x, 64x+64) so K/V (~4MB) stay L2-resident per XCD.
    const int bid  = blockIdx.x;
    const int sw   = (bid & 7) * 128 + (bid >> 3);
    const int ug   = sw >> 4;              // 0..63 u-group
    const int bt   = sw & 15;              // 0..15
    const int u0   = ug * 8;
    const int u    = u0 + wv;
    const bool ldq = (lq < 2);

    const float tl2e = temperature[u] * L2E;
    const f32x4 zf = {0.f, 0.f, 0.f, 0.f};
    const int bg = bt * 16 + lr;

    // K-frags (QK A-operand), resident: lane holds K[m=mt*16+lr][d=lq*8+j]
    bf16x8 kf[16];
    #pragma unroll
    for (int mt = 0; mt < 16; mt++) {
        bf16x8 p = {0,0,0,0,0,0,0,0};
        if (ldq) {
            const float* src = mem_att + (size_t)(mt*16 + lr) * 8192 + u * 16 + lq * 8;
            float4 v0 = *(const float4*)(src);
            float4 v1 = *(const float4*)(src + 4);
            p[0]=f2bf(v0.x); p[1]=f2bf(v0.y); p[2]=f2bf(v0.z); p[3]=f2bf(v0.w);
            p[4]=f2bf(v1.x); p[5]=f2bf(v1.y); p[6]=f2bf(v1.z); p[7]=f2bf(v1.w);
        }
        kf[mt] = p;
    }
    // att-frag (QK B-operand)
    bf16x8 af = {0,0,0,0,0,0,0,0};
    if (ldq) {
        const float* src = attention + (size_t)bg * 8192 + u * 16 + lq * 8;
        float4 v0 = *(const float4*)(src);
        float4 v1 = *(const float4*)(src + 4);
        af[0]=f2bf(v0.x); af[1]=f2bf(v0.y); af[2]=f2bf(v0.z); af[3]=f2bf(v0.w);
        af[4]=f2bf(v1.x); af[5]=f2bf(v1.y); af[6]=f2bf(v1.z); af[7]=f2bf(v1.w);
    }

    // ---- pass A: QK -> exp -> per-lane residue sums ----
    f32x4 gacc = zf;
    #pragma unroll
    for (int mt = 0; mt < 16; mt++) {
        f32x4 s = __builtin_amdgcn_mfma_f32_16x16x32_bf16(kf[mt], af, zf, 0, 0, 0);
        #pragma unroll
        for (int r = 0; r < 4; r++) {
            const int m = mt*16 + lq*4 + r;
            gacc[r] += (m == bg) ? 0.f : exp2f(s[r] * tl2e);
        }
    }
    f32x4 rinv;
    #pragma unroll
    for (int r = 0; r < 4; r++) {
        const float tot = gacc[r] + __shfl_xor(gacc[r], 32);
        rinv[r] = 1.0f / (8.0f * tot);
    }

    // ---- pass B: recompute QK per tile pair, stage w in LDS, flush, PV ----
    auto load_vpair = [&](int p) -> bf16x8 {
        const float* base = mem_val + (size_t)(p*32 + lq*4) * 8192 + u * 16 + lr;
        bf16x8 vv;
        #pragma unroll
        for (int j = 0; j < 4; j++) {
            vv[j]     = f2bf(base[(size_t)j * 8192]);
            vv[4 + j] = f2bf(base[(size_t)(16 + j) * 8192]);
        }
        return vv;
    };

    f32x4 oacc = zf;
    bf16x8 vf = load_vpair(0);

    // flush mapping: thread -> (m5 = t>>4 in 0..31, b4 = t&15), 8 u each
    const int m5 = t >> 4;
    const int b4 = t & 15;
    float* gflush = weights_out + (size_t)(bt*16 + b4) * 131072 + (size_t)m5 * 512 + u0;

    #pragma unroll 1
    for (int p2 = 0; p2 < 8; p2++) {
        const bf16x8 vcur = vf;
        if (p2 < 7) vf = load_vpair(p2 + 1);

        f32x4 sX = __builtin_amdgcn_mfma_f32_16x16x32_bf16(kf[2*p2    ], af, zf, 0, 0, 0);
        f32x4 sY = __builtin_amdgcn_mfma_f32_16x16x32_bf16(kf[2*p2 + 1], af, zf, 0, 0, 0);

        float wX[4], wY[4];
        #pragma unroll
        for (int r = 0; r < 4; r++) {
            const int mX = p2*32 + lq*4 + r;
            const int mY = mX + 16;
            wX[r] = (mX == bg) ? 0.f : exp2f(sX[r] * tl2e) * rinv[r];
            wY[r] = (mY == bg) ? 0.f : exp2f(sY[r] * tl2e) * rinv[r];
        }

        // stage into LDS: [m_local(32)][b(16)][u slot (pad 9)]
        float* Lb = wlds[p2 & 1];
        #pragma unroll
        for (int r = 0; r < 4; r++) {
            Lb[((lq*4 + r)      * 16 + lr) * UPAD + wv] = wX[r];
            Lb[((16 + lq*4 + r) * 16 + lr) * UPAD + wv] = wY[r];
        }

        // PV A-frag = own QK outputs, permuted-k: [wX0..3 | wY0..3]
        union { unsigned uu[4]; bf16x8 v; } wf;
        wf.uu[0] = pk2(wX[0], wX[1]);
        wf.uu[1] = pk2(wX[2], wX[3]);
        wf.uu[2] = pk2(wY[0], wY[1]);
        wf.uu[3] = pk2(wY[2], wY[3]);
        oacc = __builtin_amdgcn_mfma_f32_16x16x32_bf16(wf.v, vcur, oacc, 0, 0, 0);

        __syncthreads();   // all waves staged this p2 tile

        // flush: w[bt*16+b4][p2*32+m5][u0..u0+7] (two float4 = 32B per thread)
        {
            const float* Ls = &wlds[p2 & 1][(m5 * 16 + b4) * UPAD];
            float4 lo, hi;
            lo.x = Ls[0]; lo.y = Ls[1]; lo.z = Ls[2]; lo.w = Ls[3];
            hi.x = Ls[4]; hi.y = Ls[5]; hi.z = Ls[6]; hi.w = Ls[7];
            float* gp = gflush + (size_t)(p2 * 32) * 512;
            *(float4*)(gp)     = lo;
            *(float4*)(gp + 4) = hi;
        }
        // next p2 stages the other buffer; this buffer is reused at p2+2,
        // which is after the p2+1 barrier -> flush reads are complete. safe.
    }

    // outputs [b][u*16+d]
    #pragma unroll
    for (int r = 0; r < 4; r++) {
        const int bo = bt*16 + lq*4 + r;
        outputs_out[(size_t)bo * 8192 + u * 16 + lr] = oacc[r];
    }
}

// ---------------------------------------------------------------------------
extern "C" void kernel_launch(void* const* d_in, const int* in_sizes, int n_in,
                              void* d_out, int out_size, void* d_ws, size_t ws_size,
                              hipStream_t stream) {
    const float* x        = (const float*)d_in[0];  // [256,1024]
    const float* W1       = (const float*)d_in[1];  // [1024,1024]
    const float* b1       = (const float*)d_in[2];  // [1024]
    const float* W2       = (const float*)d_in[3];  // [1024,8192]
    const float* b2       = (const float*)d_in[4];  // [8192]
    const float* temp     = (const float*)d_in[5];  // [512]
    const float* mem_att  = (const float*)d_in[6];  // [256,512,16]
    const float* mem_val  = (const float*)d_in[7];  // [256,512,16]

    float* out       = (float*)d_out;
    float* attention = out;                         // 2,097,152 floats
    float* weights   = out + ATT_ELEMS;             // 33,554,432 floats
    float* outputs   = out + ATT_ELEMS + W_ELEMS;   // 2,097,152 floats

    // h [256,1024] scratch lives at the head of the weights region; it is
    // consumed by GEMM2 before the attention stage overwrites the region.
    float* h = weights;

    dim3 blk(256);
    // h = 0; h += x @ W1 (split-K x4) + b1
    zero_h<<<dim3(256), blk, 0, stream>>>((float4*)h);
    gemm1_splitk<<<dim3(DIM_GLOBAL / 64, Bq / 64, 4), blk, 0, stream>>>(
        x, W1, b1, h, Bq, DIM_GLOBAL, DIM_IN);
    // attention = h @ W2 + b2  (BK=64)
    gemm_bias_bk64<<<dim3((UNITS * DD) / 64, Bq / 64), blk, 0, stream>>>(
        h, W2, b2, attention, Bq, UNITS * DD, DIM_GLOBAL);
    // fused scores -> grouped softmax -> weights (direct) + outputs
    attn_mfma_fused<<<dim3(1024), dim3(512), 0, stream>>>(
        attention, mem_att, mem_val, temp, weights, outputs);
}